// Round 3
// baseline (933.855 us; speedup 1.0000x reference)
//
#include <hip/hip_runtime.h>
#include <hip/hip_bf16.h>
#include <stdint.h>

// GroupCommunication fused: 65536 tok x 1024 ch; 16 blocks x 64; 2 heads x 32.
// Persistent WGs (grid 512, 8 tiles of 16 tokens each), 512 thr (8 waves).
// Head-split phases so LDS = 64KB -> 2 WGs/CU; register prefetch of next
// tile's x; fragment-stream LDS layouts (linear b128 reads, swizzled writes).
// Per tile: ph1(h0) | B | ph2(h0) | B | ph3(h0)+prefetch+ph1(h1) | B |
//           ph2(h1) | B | ph3(h1)+store+repack.

typedef __attribute__((ext_vector_type(8))) short bf16x8;
typedef __attribute__((ext_vector_type(4))) float f32x4;

#define NTOK   65536
#define DM     1024
#define TT     16
#define TPW    8                       // tiles per workgroup
#define QSCALE 0.17677669529663687f    // 32^-0.5
#define LOG2E  1.4426950408889634f

static __device__ __forceinline__ unsigned short f2bf(float f) {
  unsigned int u = __float_as_uint(f);
  u += 0x7fffu + ((u >> 16) & 1u);     // RNE to bf16
  return (unsigned short)(u >> 16);
}

static __device__ __forceinline__ unsigned int pk2(float a, float b) {
  return (unsigned int)f2bf(a) | ((unsigned int)f2bf(b) << 16);
}

static __device__ __forceinline__ bf16x8 pack8(float4 a, float4 b) {
  bf16x8 r;
  r[0] = (short)f2bf(a.x); r[1] = (short)f2bf(a.y);
  r[2] = (short)f2bf(a.z); r[3] = (short)f2bf(a.w);
  r[4] = (short)f2bf(b.x); r[5] = (short)f2bf(b.y);
  r[6] = (short)f2bf(b.z); r[7] = (short)f2bf(b.w);
  return r;
}

union FragCast { uint4 u4; bf16x8 v; uint2 u2[2]; unsigned int u[4]; };

// ---------------------------------------------------------------------------
// Prologue: pack wq(scaled),wk,wv,wf fp32 [g][i][o] -> bf16 fragment stream.
// frag elem j = W[k = kk*32 + 8*(lane>>4) + j][o = nf*16 + (lane&15)].
// A- and B-side consumers always use the identical (lane,j)->k map, so any
// HW k-permutation cancels.
// ---------------------------------------------------------------------------
__global__ void build_wfrag(const float* __restrict__ wq, const float* __restrict__ wk,
                            const float* __restrict__ wv, const float* __restrict__ wf,
                            uint4* __restrict__ wfrag) {
  int tid = blockIdx.x * 256 + threadIdx.x;
  if (tid >= 4 * 16 * 2 * 4 * 64) return;
  int lane =  tid        & 63;
  int nf   = (tid >> 6)  & 3;
  int kk   = (tid >> 8)  & 1;
  int g    = (tid >> 9)  & 15;
  int mat  =  tid >> 13;
  const float* w = (mat == 0) ? wq : (mat == 1) ? wk : (mat == 2) ? wv : wf;
  float sc = (mat == 0) ? QSCALE : 1.0f;
  int o  = nf * 16 + (lane & 15);
  int kb = kk * 32 + 8 * (lane >> 4);
  unsigned int packed[4];
#pragma unroll
  for (int jj = 0; jj < 4; ++jj) {
    unsigned short lo = f2bf(w[(g * 64 + kb + 2 * jj    ) * 64 + o] * sc);
    unsigned short hi = f2bf(w[(g * 64 + kb + 2 * jj + 1) * 64 + o] * sc);
    packed[jj] = (unsigned int)lo | ((unsigned int)hi << 16);
  }
  uint4 u; u.x = packed[0]; u.y = packed[1]; u.z = packed[2]; u.w = packed[3];
  wfrag[tid] = u;
}

// ---------------------------------------------------------------------------
__global__ __launch_bounds__(512, 4)
void fused_gc(const float* __restrict__ x,
              const float* __restrict__ bq, const float* __restrict__ bk,
              const float* __restrict__ bv, const float* __restrict__ bfb,
              const uint4* __restrict__ wfrag,
              float* __restrict__ out) {
  // Per-head fragment streams: [t(16)][blk(64)] x 16B. frag(t,L) holds
  // M[t][c = L&15][d = 8*(L>>4)+j]; stored at blk = L ^ (t&7).
  __shared__ __align__(16) unsigned short s_q  [16 * 512];
  __shared__ __align__(16) unsigned short s_k  [16 * 512];
  __shared__ __align__(16) unsigned short s_att[16 * 512];
  // v stream: [t][nf(2)][L(64)] x 4 shorts; frag(t,nf,L) = V[f=4*(L>>4)+jj][d=nf*16+(L&15)]
  __shared__ __align__(16) unsigned short s_v  [16 * 2 * 64 * 4];

  const int tid  = threadIdx.x;
  const int w    = tid >> 6;      // 8 waves; g = 2w+gi, t = 2w+tt
  const int lane = tid & 63;
  const int lr   = lane & 15;
  const int lq   = lane >> 4;

  bf16x8 afr[2][2];               // [gi][kk] current tile's x fragments

  {
    const float* xr = x + ((long)blockIdx.x * (TPW * TT) + lr) * DM;
#pragma unroll
    for (int gi = 0; gi < 2; ++gi) {
      int g = 2 * w + gi;
#pragma unroll
      for (int kk = 0; kk < 2; ++kk) {
        const float* p = xr + g * 64 + kk * 32 + 8 * lq;
        afr[gi][kk] = pack8(*(const float4*)p, *(const float4*)(p + 4));
      }
    }
  }

  for (int it = 0; it < TPW; ++it) {
    const long tok0 = (long)blockIdx.x * (TPW * TT) + (long)it * TT;
    f32x4 acc[2][4];              // [gi][nf] final-linear accumulators

    // ---------------- ph1 / ph2 / ph3 bodies ----------------
    auto PH1 = [&](int h) {
#pragma unroll
      for (int gi = 0; gi < 2; ++gi) {
        int g = 2 * w + gi;
#pragma unroll
        for (int mat = 0; mat < 2; ++mat) {      // q, k (swapped orientation)
          const float* bp = mat ? bk : bq;
          float bsc = mat ? 1.0f : QSCALE;
          unsigned short* dst = mat ? s_k : s_q;
#pragma unroll
          for (int nf2 = 0; nf2 < 2; ++nf2) {
            int nf = 2 * h + nf2;
            float4 b4 = *(const float4*)&bp[g * 64 + nf * 16 + 4 * lq];
            f32x4 a1 = {b4.x * bsc, b4.y * bsc, b4.z * bsc, b4.w * bsc};
#pragma unroll
            for (int kk = 0; kk < 2; ++kk) {
              FragCast fc; fc.u4 = wfrag[(((mat * 16 + g) * 2 + kk) * 4 + nf) * 64 + lane];
              a1 = __builtin_amdgcn_mfma_f32_16x16x32_bf16(fc.v, afr[gi][kk], a1, 0, 0, 0);
            }
            // D[o][t]: col t=lr, rows o=nf*16+4lq+r -> d_h = nf2*16+4lq+r
            uint2 w2; w2.x = pk2(a1[0], a1[1]); w2.y = pk2(a1[2], a1[3]);
            int blk = (16 * (2 * nf2 + (lq >> 1)) + g) ^ (lr & 7);
            *(uint2*)&dst[lr * 512 + blk * 8 + 4 * (lq & 1)] = w2;
          }
        }
        // v (original orientation)
#pragma unroll
        for (int nf2 = 0; nf2 < 2; ++nf2) {
          int nf = 2 * h + nf2;
          float bias = bv[g * 64 + nf * 16 + lr];
          f32x4 a1 = {bias, bias, bias, bias};
#pragma unroll
          for (int kk = 0; kk < 2; ++kk) {
            FragCast fc; fc.u4 = wfrag[(((2 * 16 + g) * 2 + kk) * 4 + nf) * 64 + lane];
            a1 = __builtin_amdgcn_mfma_f32_16x16x32_bf16(afr[gi][kk], fc.v, a1, 0, 0, 0);
          }
          // D[t][o]: col o (d_h = nf2*16+lr), rows t=4lq+r; f = g
          int L = 16 * (g >> 2) + lr, jj = g & 3;
#pragma unroll
          for (int r = 0; r < 4; ++r)
            s_v[((4 * lq + r) * 2 + nf2) * 256 + L * 4 + jj] = f2bf(a1[r]);
        }
      }
    };

    auto PH2 = [&](int h) {
      (void)h;
#pragma unroll
      for (int tt = 0; tt < 2; ++tt) {
        int t = 2 * w + tt;
        f32x4 zero = {0.f, 0.f, 0.f, 0.f};
        FragCast qa, ka;
        int blk = lane ^ (t & 7);
        qa.u4 = *(const uint4*)&s_q[t * 512 + blk * 8];
        ka.u4 = *(const uint4*)&s_k[t * 512 + blk * 8];
        // D[f][g]: col g=lr, rows f=4lq+r (K=32 = full head dim)
        f32x4 sc4 = __builtin_amdgcn_mfma_f32_16x16x32_bf16(ka.v, qa.v, zero, 0, 0, 0);
        float m = fmaxf(fmaxf(sc4[0], sc4[1]), fmaxf(sc4[2], sc4[3]));
        m = fmaxf(m, __shfl_xor(m, 16));
        m = fmaxf(m, __shfl_xor(m, 32));
        float p0 = exp2f((sc4[0] - m) * LOG2E);
        float p1 = exp2f((sc4[1] - m) * LOG2E);
        float p2 = exp2f((sc4[2] - m) * LOG2E);
        float p3 = exp2f((sc4[3] - m) * LOG2E);
        float s = p0 + p1 + p2 + p3;
        s += __shfl_xor(s, 16);
        s += __shfl_xor(s, 32);
        float inv = __fdividef(1.0f, s);
        FragCast pa;                 // P[g=lr][f=4lq+jj] at slots jj 0..3
        pa.u[0] = pk2(p0 * inv, p1 * inv);
        pa.u[1] = pk2(p2 * inv, p3 * inv);
        pa.u[2] = 0; pa.u[3] = 0;
#pragma unroll
        for (int nf = 0; nf < 2; ++nf) {
          FragCast va;               // V[f=4lq+jj][d=nf*16+lr] at slots jj 0..3
          va.u2[0] = *(const uint2*)&s_v[(t * 2 + nf) * 256 + lane * 4];
          va.u[2] = 0; va.u[3] = 0;
          f32x4 o4 = __builtin_amdgcn_mfma_f32_16x16x32_bf16(va.v, pa.v, zero, 0, 0, 0);
          // D[d][g]: col g=lr, rows d=nf*16+4lq+r
          uint2 w2; w2.x = pk2(o4[0], o4[1]); w2.y = pk2(o4[2], o4[3]);
          int ablk = (16 * (2 * nf + (lq >> 1)) + lr) ^ (t & 7);
          *(uint2*)&s_att[t * 512 + ablk * 8 + 4 * (lq & 1)] = w2;
        }
      }
    };

    auto PH3 = [&](int h) {
#pragma unroll
      for (int gi = 0; gi < 2; ++gi) {
        int g = 2 * w + gi;
        FragCast aa;                 // att[t=lr][g][d=8lq+j] -> B[k][t]
        int blk = (16 * lq + g) ^ (lr & 7);
        aa.u4 = *(const uint4*)&s_att[lr * 512 + blk * 8];
#pragma unroll
        for (int nf = 0; nf < 4; ++nf) {
          FragCast fc; fc.u4 = wfrag[(((3 * 16 + g) * 2 + h) * 4 + nf) * 64 + lane];
          acc[gi][nf] = __builtin_amdgcn_mfma_f32_16x16x32_bf16(fc.v, aa.v, acc[gi][nf], 0, 0, 0);
        }
      }
    };

    // ---------------- schedule ----------------
    PH1(0);
    __syncthreads();
    PH2(0);
    __syncthreads();

    // init acc with final bias, consume att(h0), prefetch next x, build h1
#pragma unroll
    for (int gi = 0; gi < 2; ++gi) {
      int g = 2 * w + gi;
#pragma unroll
      for (int nf = 0; nf < 4; ++nf) {
        float4 b4 = *(const float4*)&bfb[g * 64 + nf * 16 + 4 * lq];
        acc[gi][nf][0] = b4.x; acc[gi][nf][1] = b4.y;
        acc[gi][nf][2] = b4.z; acc[gi][nf][3] = b4.w;
      }
    }
    PH3(0);

    float4 xn[2][2][2];
    const bool pf = (it + 1 < TPW);
    if (pf) {
      const float* xr = x + (tok0 + TT + lr) * DM;
#pragma unroll
      for (int gi = 0; gi < 2; ++gi) {
        int g = 2 * w + gi;
#pragma unroll
        for (int kk = 0; kk < 2; ++kk) {
          const float* p = xr + g * 64 + kk * 32 + 8 * lq;
          xn[gi][kk][0] = *(const float4*)p;
          xn[gi][kk][1] = *(const float4*)(p + 4);
        }
      }
    }

    PH1(1);
    __syncthreads();
    PH2(1);
    __syncthreads();
    PH3(1);

    // store out (fp32, float4 per nf)
#pragma unroll
    for (int gi = 0; gi < 2; ++gi) {
      int g = 2 * w + gi;
#pragma unroll
      for (int nf = 0; nf < 4; ++nf) {
        float4 o4;
        o4.x = acc[gi][nf][0]; o4.y = acc[gi][nf][1];
        o4.z = acc[gi][nf][2]; o4.w = acc[gi][nf][3];
        *(float4*)&out[(tok0 + lr) * DM + g * 64 + nf * 16 + 4 * lq] = o4;
      }
    }

    if (pf) {
#pragma unroll
      for (int gi = 0; gi < 2; ++gi)
#pragma unroll
        for (int kk = 0; kk < 2; ++kk)
          afr[gi][kk] = pack8(xn[gi][kk][0], xn[gi][kk][1]);
    }
  }
}

// ---------------------------------------------------------------------------
extern "C" void kernel_launch(void* const* d_in, const int* in_sizes, int n_in,
                              void* d_out, int out_size, void* d_ws, size_t ws_size,
                              hipStream_t stream) {
  const float* x   = (const float*)d_in[0];
  const float* wq  = (const float*)d_in[1];
  const float* bq_ = (const float*)d_in[2];
  const float* wk  = (const float*)d_in[3];
  const float* bk_ = (const float*)d_in[4];
  const float* wv  = (const float*)d_in[5];
  const float* bv_ = (const float*)d_in[6];
  const float* wf  = (const float*)d_in[7];
  const float* bf_ = (const float*)d_in[8];
  (void)in_sizes; (void)n_in; (void)out_size; (void)ws_size;

  uint4* wfrag = (uint4*)d_ws;   // 4*16*2*4*64 frags * 16B = 512 KiB

  build_wfrag<<<128, 256, 0, stream>>>(wq, wk, wv, wf, wfrag);
  fused_gc<<<NTOK / (TPW * TT), 512, 0, stream>>>(x, bq_, bk_, bv_, bf_, wfrag,
                                                  (float*)d_out);
}

// Round 4
// 234.713 us; speedup vs baseline: 3.9787x; 3.9787x over previous
//
#include <hip/hip_runtime.h>
#include <hip/hip_bf16.h>
#include <stdint.h>

// GroupCommunication fused: 65536 tok x 1024 ch; 16 blocks x 64; 2 heads x 32.
// Grid 4096 x 512 thr (8 waves). Head-split phases -> LDS 64KB -> 2 WGs/CU
// (two independent barrier domains per CU for latency overlap).
// Schedule per tile: PH1(h0) |B| PH2 |B| accinit+PH3(h0)+PH1(h1) |B| PH2 |B|
// PH3(h1)+store.  All phase bodies are macros (no lambdas) so every array
// index is compile-time -> no scratch (R3's 934us was lambda/prefetch spill:
// WRITE_SIZE 264->658MB).

typedef __attribute__((ext_vector_type(8))) short bf16x8;
typedef __attribute__((ext_vector_type(4))) float f32x4;

#define NTOK   65536
#define DM     1024
#define TT     16
#define QSCALE 0.17677669529663687f    // 32^-0.5
#define LOG2E  1.4426950408889634f

static __device__ __forceinline__ unsigned short f2bf(float f) {
  unsigned int u = __float_as_uint(f);
  u += 0x7fffu + ((u >> 16) & 1u);     // RNE to bf16
  return (unsigned short)(u >> 16);
}

static __device__ __forceinline__ unsigned int pk2(float a, float b) {
  return (unsigned int)f2bf(a) | ((unsigned int)f2bf(b) << 16);
}

static __device__ __forceinline__ bf16x8 pack8(float4 a, float4 b) {
  bf16x8 r;
  r[0] = (short)f2bf(a.x); r[1] = (short)f2bf(a.y);
  r[2] = (short)f2bf(a.z); r[3] = (short)f2bf(a.w);
  r[4] = (short)f2bf(b.x); r[5] = (short)f2bf(b.y);
  r[6] = (short)f2bf(b.z); r[7] = (short)f2bf(b.w);
  return r;
}

union FragCast { uint4 u4; bf16x8 v; uint2 u2[2]; unsigned int u[4]; };

// ---------------------------------------------------------------------------
// Prologue: pack wq(scaled),wk,wv,wf fp32 [g][i][o] -> bf16 fragment stream.
// frag elem j = W[k = kk*32 + 8*(lane>>4) + j][o = nf*16 + (lane&15)].
// A- and B-side consumers always use the identical (lane,j)->k map, so any
// HW k-permutation cancels.
// ---------------------------------------------------------------------------
__global__ void build_wfrag(const float* __restrict__ wq, const float* __restrict__ wk,
                            const float* __restrict__ wv, const float* __restrict__ wf,
                            uint4* __restrict__ wfrag) {
  int tid = blockIdx.x * 256 + threadIdx.x;
  if (tid >= 4 * 16 * 2 * 4 * 64) return;
  int lane =  tid        & 63;
  int nf   = (tid >> 6)  & 3;
  int kk   = (tid >> 8)  & 1;
  int g    = (tid >> 9)  & 15;
  int mat  =  tid >> 13;
  const float* w = (mat == 0) ? wq : (mat == 1) ? wk : (mat == 2) ? wv : wf;
  float sc = (mat == 0) ? QSCALE : 1.0f;
  int o  = nf * 16 + (lane & 15);
  int kb = kk * 32 + 8 * (lane >> 4);
  unsigned int packed[4];
#pragma unroll
  for (int jj = 0; jj < 4; ++jj) {
    unsigned short lo = f2bf(w[(g * 64 + kb + 2 * jj    ) * 64 + o] * sc);
    unsigned short hi = f2bf(w[(g * 64 + kb + 2 * jj + 1) * 64 + o] * sc);
    packed[jj] = (unsigned int)lo | ((unsigned int)hi << 16);
  }
  uint4 u; u.x = packed[0]; u.y = packed[1]; u.z = packed[2]; u.w = packed[3];
  wfrag[tid] = u;
}

// ---------------------------------------------------------------------------
// Phase macros (textual expansion; h_ must be a literal 0/1).
// ---------------------------------------------------------------------------
#define PH1(h_) do {                                                          \
  _Pragma("unroll")                                                           \
  for (int gi = 0; gi < 2; ++gi) {                                            \
    const int g = 2 * w + gi;                                                 \
    _Pragma("unroll")                                                         \
    for (int mat = 0; mat < 2; ++mat) {      /* q, k (swapped orientation) */ \
      const float* bp = mat ? bk : bq;                                        \
      const float bsc = mat ? 1.0f : QSCALE;                                  \
      unsigned short* dst = mat ? s_k : s_q;                                  \
      _Pragma("unroll")                                                       \
      for (int nf2 = 0; nf2 < 2; ++nf2) {                                     \
        const int nf = 2 * (h_) + nf2;                                        \
        float4 b4 = *(const float4*)&bp[g * 64 + nf * 16 + 4 * lq];           \
        f32x4 a1 = {b4.x * bsc, b4.y * bsc, b4.z * bsc, b4.w * bsc};          \
        _Pragma("unroll")                                                     \
        for (int kk = 0; kk < 2; ++kk) {                                      \
          FragCast fc;                                                        \
          fc.u4 = wfrag[(((mat * 16 + g) * 2 + kk) * 4 + nf) * 64 + lane];    \
          a1 = __builtin_amdgcn_mfma_f32_16x16x32_bf16(fc.v, afr[gi][kk], a1, 0, 0, 0); \
        }                                                                     \
        /* D[o][t]: col t=lr, rows o=nf*16+4lq+r -> d_h = nf2*16+4lq+r */     \
        uint2 w2; w2.x = pk2(a1[0], a1[1]); w2.y = pk2(a1[2], a1[3]);         \
        const int blk = (16 * (2 * nf2 + (lq >> 1)) + g) ^ (lr & 7);          \
        *(uint2*)&dst[lr * 512 + blk * 8 + 4 * (lq & 1)] = w2;                \
      }                                                                       \
    }                                                                         \
    _Pragma("unroll")                                                         \
    for (int nf2 = 0; nf2 < 2; ++nf2) {      /* v (original orientation) */   \
      const int nf = 2 * (h_) + nf2;                                          \
      const float bias = bv[g * 64 + nf * 16 + lr];                           \
      f32x4 a1 = {bias, bias, bias, bias};                                    \
      _Pragma("unroll")                                                       \
      for (int kk = 0; kk < 2; ++kk) {                                        \
        FragCast fc;                                                          \
        fc.u4 = wfrag[(((2 * 16 + g) * 2 + kk) * 4 + nf) * 64 + lane];        \
        a1 = __builtin_amdgcn_mfma_f32_16x16x32_bf16(afr[gi][kk], fc.v, a1, 0, 0, 0); \
      }                                                                       \
      /* D[t][o]: col o (d_h = nf2*16+lr), rows t=4lq+r; f = g */             \
      const int L = 16 * (g >> 2) + lr;                                       \
      const int jj = g & 3;                                                   \
      _Pragma("unroll")                                                       \
      for (int r = 0; r < 4; ++r)                                             \
        s_v[((4 * lq + r) * 2 + nf2) * 256 + L * 4 + jj] = f2bf(a1[r]);       \
    }                                                                         \
  }                                                                           \
} while (0)

#define PH2() do {                                                            \
  _Pragma("unroll")                                                           \
  for (int tt = 0; tt < 2; ++tt) {                                            \
    const int t = 2 * w + tt;                                                 \
    f32x4 zero = {0.f, 0.f, 0.f, 0.f};                                        \
    FragCast qa, ka;                                                          \
    const int blk = lane ^ (t & 7);                                           \
    qa.u4 = *(const uint4*)&s_q[t * 512 + blk * 8];                           \
    ka.u4 = *(const uint4*)&s_k[t * 512 + blk * 8];                           \
    /* D[f][g]: col g=lr, rows f=4lq+r (K=32 = full head dim) */              \
    f32x4 sc4 = __builtin_amdgcn_mfma_f32_16x16x32_bf16(ka.v, qa.v, zero, 0, 0, 0); \
    float m = fmaxf(fmaxf(sc4[0], sc4[1]), fmaxf(sc4[2], sc4[3]));            \
    m = fmaxf(m, __shfl_xor(m, 16));                                          \
    m = fmaxf(m, __shfl_xor(m, 32));                                          \
    float p0 = exp2f((sc4[0] - m) * LOG2E);                                   \
    float p1 = exp2f((sc4[1] - m) * LOG2E);                                   \
    float p2 = exp2f((sc4[2] - m) * LOG2E);                                   \
    float p3 = exp2f((sc4[3] - m) * LOG2E);                                   \
    float s = p0 + p1 + p2 + p3;                                              \
    s += __shfl_xor(s, 16);                                                   \
    s += __shfl_xor(s, 32);                                                   \
    const float inv = __fdividef(1.0f, s);                                    \
    FragCast pa;               /* P[g=lr][f=4lq+jj] at slots jj 0..3 */       \
    pa.u[0] = pk2(p0 * inv, p1 * inv);                                        \
    pa.u[1] = pk2(p2 * inv, p3 * inv);                                        \
    pa.u[2] = 0; pa.u[3] = 0;                                                 \
    _Pragma("unroll")                                                         \
    for (int nf = 0; nf < 2; ++nf) {                                          \
      FragCast va;             /* V[f=4lq+jj][d=nf*16+lr] at slots jj 0..3 */ \
      va.u2[0] = *(const uint2*)&s_v[(t * 2 + nf) * 256 + lane * 4];          \
      va.u[2] = 0; va.u[3] = 0;                                               \
      f32x4 o4 = __builtin_amdgcn_mfma_f32_16x16x32_bf16(va.v, pa.v, zero, 0, 0, 0); \
      /* D[d][g]: col g=lr, rows d=nf*16+4lq+r */                             \
      uint2 w2; w2.x = pk2(o4[0], o4[1]); w2.y = pk2(o4[2], o4[3]);           \
      const int ablk = (16 * (2 * nf + (lq >> 1)) + lr) ^ (t & 7);            \
      *(uint2*)&s_att[t * 512 + ablk * 8 + 4 * (lq & 1)] = w2;                \
    }                                                                         \
  }                                                                           \
} while (0)

#define PH3(h_) do {                                                          \
  _Pragma("unroll")                                                           \
  for (int gi = 0; gi < 2; ++gi) {                                            \
    const int g = 2 * w + gi;                                                 \
    FragCast aa;               /* att[t=lr][g][d=8lq+j] -> B[k][t] */         \
    const int blk = (16 * lq + g) ^ (lr & 7);                                 \
    aa.u4 = *(const uint4*)&s_att[lr * 512 + blk * 8];                        \
    _Pragma("unroll")                                                         \
    for (int nf = 0; nf < 4; ++nf) {                                          \
      FragCast fc;                                                            \
      fc.u4 = wfrag[(((3 * 16 + g) * 2 + (h_)) * 4 + nf) * 64 + lane];        \
      acc[gi][nf] = __builtin_amdgcn_mfma_f32_16x16x32_bf16(fc.v, aa.v, acc[gi][nf], 0, 0, 0); \
    }                                                                         \
  }                                                                           \
} while (0)

// ---------------------------------------------------------------------------
__global__ __launch_bounds__(512, 4)
void fused_gc(const float* __restrict__ x,
              const float* __restrict__ bq, const float* __restrict__ bk,
              const float* __restrict__ bv, const float* __restrict__ bfb,
              const uint4* __restrict__ wfrag,
              float* __restrict__ out) {
  // Per-head fragment streams: [t(16)][blk(64)] x 16B. frag(t,L) holds
  // M[t][c = L&15][d = 8*(L>>4)+j]; stored at blk = L ^ (t&7).   16KB each.
  __shared__ __align__(16) unsigned short s_q  [16 * 512];
  __shared__ __align__(16) unsigned short s_k  [16 * 512];
  __shared__ __align__(16) unsigned short s_att[16 * 512];
  // v stream: [t][nf(2)][L(64)] x 4 shorts; frag = V[f=4*(L>>4)+jj][d=nf*16+(L&15)]
  __shared__ __align__(16) unsigned short s_v  [16 * 2 * 64 * 4];

  const int tid  = threadIdx.x;
  const int w    = tid >> 6;      // 8 waves; g = 2w+gi, t = 2w+tt
  const int lane = tid & 63;
  const int lr   = lane & 15;
  const int lq   = lane >> 4;
  const long tok0 = (long)blockIdx.x * TT;

  // x fragments for this tile: lane's token row = lr
  bf16x8 afr[2][2];
  {
    const float* xr = x + (tok0 + lr) * DM;
#pragma unroll
    for (int gi = 0; gi < 2; ++gi) {
      const int g = 2 * w + gi;
#pragma unroll
      for (int kk = 0; kk < 2; ++kk) {
        const float* p = xr + g * 64 + kk * 32 + 8 * lq;
        afr[gi][kk] = pack8(*(const float4*)p, *(const float4*)(p + 4));
      }
    }
  }

  f32x4 acc[2][4];                // [gi][nf] final-linear accumulators

  PH1(0);
  __syncthreads();
  PH2();
  __syncthreads();

  // init acc with final bias; consume att(h0); build h1 inputs (no hazard:
  // PH3 reads s_att, PH1 writes s_q/s_k/s_v)
#pragma unroll
  for (int gi = 0; gi < 2; ++gi) {
    const int g = 2 * w + gi;
#pragma unroll
    for (int nf = 0; nf < 4; ++nf) {
      float4 b4 = *(const float4*)&bfb[g * 64 + nf * 16 + 4 * lq];
      acc[gi][nf][0] = b4.x; acc[gi][nf][1] = b4.y;
      acc[gi][nf][2] = b4.z; acc[gi][nf][3] = b4.w;
    }
  }
  PH3(0);
  PH1(1);
  __syncthreads();
  PH2();
  __syncthreads();
  PH3(1);

  // store out: D[o][t] -> one float4 per nf
#pragma unroll
  for (int gi = 0; gi < 2; ++gi) {
    const int g = 2 * w + gi;
#pragma unroll
    for (int nf = 0; nf < 4; ++nf) {
      float4 o4;
      o4.x = acc[gi][nf][0]; o4.y = acc[gi][nf][1];
      o4.z = acc[gi][nf][2]; o4.w = acc[gi][nf][3];
      *(float4*)&out[(tok0 + lr) * DM + g * 64 + nf * 16 + 4 * lq] = o4;
    }
  }
}

// ---------------------------------------------------------------------------
extern "C" void kernel_launch(void* const* d_in, const int* in_sizes, int n_in,
                              void* d_out, int out_size, void* d_ws, size_t ws_size,
                              hipStream_t stream) {
  const float* x   = (const float*)d_in[0];
  const float* wq  = (const float*)d_in[1];
  const float* bq_ = (const float*)d_in[2];
  const float* wk  = (const float*)d_in[3];
  const float* bk_ = (const float*)d_in[4];
  const float* wv  = (const float*)d_in[5];
  const float* bv_ = (const float*)d_in[6];
  const float* wf  = (const float*)d_in[7];
  const float* bf_ = (const float*)d_in[8];
  (void)in_sizes; (void)n_in; (void)out_size; (void)ws_size;

  uint4* wfrag = (uint4*)d_ws;   // 4*16*2*4*64 frags * 16B = 512 KiB

  build_wfrag<<<128, 256, 0, stream>>>(wq, wk, wv, wf, wfrag);
  fused_gc<<<NTOK / TT, 512, 0, stream>>>(x, bq_, bk_, bv_, bf_, wfrag,
                                          (float*)d_out);
}